// Round 7
// baseline (59.315 us; speedup 1.0000x reference)
//
#include <hip/hip_runtime.h>
#include <math.h>

#define NE 4096
#define NROWS_STATE 160   // 5 * 32 layers

// ws layout (floats)
#define WS_KK   0
#define WS_VV   (NE)
#define WS_RR   (2*NE)
#define WS_RWKV (3*NE)

__device__ __forceinline__ float wave_reduce_sum(float v) {
    #pragma unroll
    for (int off = 32; off > 0; off >>= 1)
        v += __shfl_down(v, off, 64);
    return v;  // valid in lane 0
}

// ---------------- kernel A: fused LN + time-mix + 3-matrix matvec ----------------
// grid = 3072 matvec blocks + 16 aux blocks.
// matvec block b in [0,3072): m = b>>10, row group = (b&1023)*4 .. +3; 4 waves = 4 rows.
//   Every block recomputes LN stats from the 16KB input (L2 broadcast) so weight
//   streaming starts at t=0 with no serial LN kernel ahead of it.
// aux block b in [3072,3088): writes x (post-LN) into out_state row 5*li+1.
__global__ void __launch_bounds__(256)
k_ln_matvec3(const float* __restrict__ in, const float* __restrict__ state,
             const float* __restrict__ tmk, const float* __restrict__ tmv,
             const float* __restrict__ tmr, const float* __restrict__ lnw,
             const float* __restrict__ lnb, const int* __restrict__ layer,
             const float* __restrict__ kw, const float* __restrict__ vw,
             const float* __restrict__ rw, float* __restrict__ out_state,
             float* __restrict__ ws_out) {
    __shared__ float4 sx[NE / 4];     // 16 KB: mixed x-vector for this block's matrix
    __shared__ float sred[8];
    __shared__ float s_stats[2];
    int t = threadIdx.x, lane = t & 63, wid = t >> 6;
    int li = layer[0];

    // --- LN stats (every block) ---
    float4 v[4];
    float sum = 0.0f, sumsq = 0.0f;
    #pragma unroll
    for (int j = 0; j < 4; ++j) {
        v[j] = ((const float4*)in)[t * 4 + j];
        sum   += v[j].x + v[j].y + v[j].z + v[j].w;
        sumsq += v[j].x*v[j].x + v[j].y*v[j].y + v[j].z*v[j].z + v[j].w*v[j].w;
    }
    float s1 = wave_reduce_sum(sum);
    float s2 = wave_reduce_sum(sumsq);
    if (lane == 0) { sred[wid] = s1; sred[4 + wid] = s2; }
    __syncthreads();
    if (t == 0) {
        float tot  = sred[0] + sred[1] + sred[2] + sred[3];
        float tot2 = sred[4] + sred[5] + sred[6] + sred[7];
        float mu  = tot * (1.0f / NE);
        float var = tot2 * (1.0f / NE) - mu * mu;
        s_stats[0] = mu;
        s_stats[1] = rsqrtf(var + 1e-5f);
    }
    __syncthreads();
    float mu = s_stats[0], rstd = s_stats[1];

    if (blockIdx.x >= 3072) {
        // --- aux: write x row (5*li+1) ---
        int e = (blockIdx.x - 3072) * 256 + t;
        float x = (in[e] - mu) * rstd * lnw[e] + lnb[e];
        out_state[(size_t)(5 * li + 1) * NE + e] = x;
        return;
    }

    int m    = blockIdx.x >> 10;
    int rowg = blockIdx.x & 1023;
    const float* tm = (m == 0) ? tmk : (m == 1) ? tmv : tmr;
    const float* prev_row = state + (size_t)(5 * li + 1) * NE;

    // --- mix into LDS: thread t covers float4 indices t*4..t*4+3 ---
    #pragma unroll
    for (int j = 0; j < 4; ++j) {
        int i4 = t * 4 + j;
        float4 xin = v[j];
        float4 tm4 = ((const float4*)tm)[i4];
        float4 pv4 = ((const float4*)prev_row)[i4];
        float4 lw4 = ((const float4*)lnw)[i4];
        float4 lb4 = ((const float4*)lnb)[i4];
        float4 r;
        r.x = ((xin.x - mu) * rstd * lw4.x + lb4.x) * tm4.x + pv4.x * (1.0f - tm4.x);
        r.y = ((xin.y - mu) * rstd * lw4.y + lb4.y) * tm4.y + pv4.y * (1.0f - tm4.y);
        r.z = ((xin.z - mu) * rstd * lw4.z + lb4.z) * tm4.z + pv4.z * (1.0f - tm4.z);
        r.w = ((xin.w - mu) * rstd * lw4.w + lb4.w) * tm4.w + pv4.w * (1.0f - tm4.w);
        sx[i4] = r;
    }
    __syncthreads();

    // --- full-row dot per wave ---
    int row = rowg * 4 + wid;
    const float* W = (m == 0) ? kw : (m == 1) ? vw : rw;
    const float4* Wr = (const float4*)(W + (size_t)row * NE);
    float acc = 0.0f;
    #pragma unroll
    for (int i = 0; i < 16; ++i) {
        float4 w4 = Wr[i * 64 + lane];
        float4 x4 = sx[i * 64 + lane];
        acc += w4.x*x4.x + w4.y*x4.y + w4.z*x4.z + w4.w*x4.w;
    }
    acc = wave_reduce_sum(acc);
    if (lane == 0) ws_out[m * NE + row] = acc;
}

// ---------------- kernel B: WKV elementwise + state update + state copy ----------------
// blocks 0..15: wkv for elems b*256+t; blocks 16..655: copy state (skip rows 5li+1..+4)
__global__ void __launch_bounds__(256)
k_wkv_copy(const float* __restrict__ state, const float* __restrict__ tf,
           const float* __restrict__ td, const int* __restrict__ layer,
           const float* __restrict__ ws, float* __restrict__ out_state,
           float* __restrict__ rwkv) {
    int li = layer[0];
    if (blockIdx.x >= 16) {
        int i4 = (blockIdx.x - 16) * 256 + threadIdx.x;   // float4 index, 1024 per row
        int row = i4 >> 10;
        if (row < 5 * li + 1 || row > 5 * li + 4) {
            ((float4*)out_state)[i4] = ((const float4*)state)[i4];
        }
        return;
    }
    int idx = blockIdx.x * 256 + threadIdx.x;
    float kk = ws[WS_KK + idx];
    float vv = ws[WS_VV + idx];
    float r  = 1.0f / (1.0f + expf(-ws[WS_RR + idx]));
    float aa = state[(size_t)(5 * li + 2) * NE + idx];
    float bb = state[(size_t)(5 * li + 3) * NE + idx];
    float pp = state[(size_t)(5 * li + 4) * NE + idx];

    float ww = tf[idx] + kk;
    float p  = fmaxf(pp, ww);
    float e1 = expf(pp - p);
    float e2 = expf(ww - p);
    float a  = e1 * aa + e2 * vv;
    float b  = e1 * bb + e2;

    float ww2 = pp + td[idx];
    float p2  = fmaxf(ww2, kk);
    float e1s = expf(ww2 - p2);
    float e2s = expf(kk - p2);
    out_state[(size_t)(5 * li + 2) * NE + idx] = e1s * aa + e2s * vv;
    out_state[(size_t)(5 * li + 3) * NE + idx] = e1s * bb + e2s;
    out_state[(size_t)(5 * li + 4) * NE + idx] = p2;

    rwkv[idx] = r * (a / b);
}

// ---------------- kernel C: output matvec, full-row waves, rwkv in LDS ----------------
__global__ void __launch_bounds__(256)
k_matvec_ow(const float* __restrict__ ow, const float* __restrict__ rwkv,
            float* __restrict__ out) {
    __shared__ float4 sx[NE / 4];           // 16 KB
    int t    = threadIdx.x;
    int lane = t & 63;
    int row  = blockIdx.x * 4 + (t >> 6);
    #pragma unroll
    for (int j = 0; j < 4; ++j) sx[t + j * 256] = ((const float4*)rwkv)[t + j * 256];
    __syncthreads();

    const float4* Wr = (const float4*)(ow + (size_t)row * NE);
    float acc = 0.0f;
    #pragma unroll
    for (int i = 0; i < 16; ++i) {
        float4 w4 = Wr[i * 64 + lane];
        float4 x4 = sx[i * 64 + lane];
        acc += w4.x*x4.x + w4.y*x4.y + w4.z*x4.z + w4.w*x4.w;
    }
    acc = wave_reduce_sum(acc);
    if (lane == 0) out[row] = acc;
}

extern "C" void kernel_launch(void* const* d_in, const int* in_sizes, int n_in,
                              void* d_out, int out_size, void* d_ws, size_t ws_size,
                              hipStream_t stream) {
    const float* input = (const float*)d_in[0];
    const float* state = (const float*)d_in[1];
    const float* tmk   = (const float*)d_in[2];
    const float* tmv   = (const float*)d_in[3];
    const float* tmr   = (const float*)d_in[4];
    const float* tf    = (const float*)d_in[5];
    const float* td    = (const float*)d_in[6];
    const float* kw    = (const float*)d_in[7];
    const float* vw    = (const float*)d_in[8];
    const float* rw    = (const float*)d_in[9];
    const float* ow    = (const float*)d_in[10];
    const float* lnw   = (const float*)d_in[11];
    const float* lnb   = (const float*)d_in[12];
    const int*   layer = (const int*)d_in[13];

    float* out_state = (float*)d_out;                            // 160*4096 floats
    float* out_vec   = (float*)d_out + (size_t)NROWS_STATE * NE; // 4096 floats
    float* ws        = (float*)d_ws;

    // A. LN + mix fused into the kk/vv/rr matvecs (+ aux x-row write)
    k_ln_matvec3<<<3088, 256, 0, stream>>>(input, state, tmk, tmv, tmr, lnw, lnb,
                                           layer, kw, vw, rw, out_state, ws + WS_KK);
    // B. WKV recurrence + sigmoid + state copy
    k_wkv_copy<<<656, 256, 0, stream>>>(state, tf, td, layer, ws, out_state,
                                        ws + WS_RWKV);
    // C. out = ow @ (r * wkv)
    k_matvec_ow<<<NE / 4, 256, 0, stream>>>(ow, ws + WS_RWKV, out_vec);
}

// Round 8
// 58.735 us; speedup vs baseline: 1.0099x; 1.0099x over previous
//
#include <hip/hip_runtime.h>
#include <math.h>

#define NE 4096
#define NROWS_STATE 160   // 5 * 32 layers

// ws layout (floats)
#define WS_XK   0
#define WS_XV   (NE)
#define WS_XR   (2*NE)
#define WS_RWKV (3*NE)

__device__ __forceinline__ float wave_reduce_sum(float v) {
    #pragma unroll
    for (int off = 32; off > 0; off >>= 1)
        v += __shfl_down(v, off, 64);
    return v;  // valid in lane 0
}

// ---------------- kernel 1: state copy + LN + time-mix ----------------
// block 0: LN + mix (256 threads, 16 elems each); blocks 1..640: state copy
__global__ void __launch_bounds__(256)
k_copy_ln_mix(const float* __restrict__ in, const float* __restrict__ state,
              const float* __restrict__ tmk, const float* __restrict__ tmv,
              const float* __restrict__ tmr, const float* __restrict__ lnw,
              const float* __restrict__ lnb, const int* __restrict__ layer,
              float* __restrict__ out_state, float* __restrict__ ws) {
    int li = layer[0];
    if (blockIdx.x != 0) {
        int i4 = (blockIdx.x - 1) * 256 + threadIdx.x;   // float4 index, 1024 per row
        int row = i4 >> 10;
        if (row < 5 * li + 1 || row > 5 * li + 4) {
            ((float4*)out_state)[i4] = ((const float4*)state)[i4];
        }
        return;
    }
    __shared__ float sm1[4];
    __shared__ float sm2[4];
    __shared__ float s_mu, s_rstd;
    int t = threadIdx.x;
    int lane = t & 63, wid = t >> 6;

    float4 v[4];
    float sum = 0.0f, sumsq = 0.0f;
    #pragma unroll
    for (int j = 0; j < 4; ++j) {
        v[j] = ((const float4*)in)[t * 4 + j];
        sum   += v[j].x + v[j].y + v[j].z + v[j].w;
        sumsq += v[j].x*v[j].x + v[j].y*v[j].y + v[j].z*v[j].z + v[j].w*v[j].w;
    }
    float s1 = wave_reduce_sum(sum);
    float s2 = wave_reduce_sum(sumsq);
    if (lane == 0) { sm1[wid] = s1; sm2[wid] = s2; }
    __syncthreads();
    if (t == 0) {
        float tot  = sm1[0] + sm1[1] + sm1[2] + sm1[3];
        float tot2 = sm2[0] + sm2[1] + sm2[2] + sm2[3];
        float mu  = tot * (1.0f / NE);
        float var = tot2 * (1.0f / NE) - mu * mu;
        s_mu = mu;
        s_rstd = rsqrtf(var + 1e-5f);
    }
    __syncthreads();
    float mu = s_mu, rstd = s_rstd;

    const float* prev_row = state + (size_t)(5 * li + 1) * NE;
    float* x_row = out_state + (size_t)(5 * li + 1) * NE;

    #pragma unroll
    for (int j = 0; j < 4; ++j) {
        #pragma unroll
        for (int c = 0; c < 4; ++c) {
            int idx = t * 16 + j * 4 + c;
            float xin = (c == 0) ? v[j].x : (c == 1) ? v[j].y : (c == 2) ? v[j].z : v[j].w;
            float x    = (xin - mu) * rstd * lnw[idx] + lnb[idx];
            float prev = prev_row[idx];
            float mk = tmk[idx], mv = tmv[idx], mr = tmr[idx];
            ws[WS_XK + idx] = x * mk + prev * (1.0f - mk);
            ws[WS_XV + idx] = x * mv + prev * (1.0f - mv);
            ws[WS_XR + idx] = x * mr + prev * (1.0f - mr);
            x_row[idx] = x;
        }
    }
}

// ---------------- kernel 2: fused 3-matrix matvec + WKV ----------------
// One wave per OUTPUT INDEX r: computes kw[r]·xk, vw[r]·xv, rw[r]·xr (48 KB
// weight stream), then lane 0 runs the scalar WKV recurrence for element r and
// writes rwkv[r] + the three state rows. No atomics, no intermediate round-trip.
// grid = 1024 blocks of 256 (4 waves = 4 rows).
__global__ void __launch_bounds__(256)
k_matvec3_wkv(const float* __restrict__ kw, const float* __restrict__ vw,
              const float* __restrict__ rw, const float* __restrict__ ws,
              const float* __restrict__ state, const float* __restrict__ tf,
              const float* __restrict__ td, const int* __restrict__ layer,
              float* __restrict__ out_state, float* __restrict__ rwkv) {
    int t    = threadIdx.x;
    int lane = t & 63;
    int row  = blockIdx.x * 4 + (t >> 6);

    const float4* Wk = (const float4*)(kw + (size_t)row * NE);
    const float4* Wv = (const float4*)(vw + (size_t)row * NE);
    const float4* Wr = (const float4*)(rw + (size_t)row * NE);
    const float4* xk = (const float4*)(ws + WS_XK);
    const float4* xv = (const float4*)(ws + WS_XV);
    const float4* xr = (const float4*)(ws + WS_XR);

    float ak = 0.0f, av = 0.0f, ar = 0.0f;
    #pragma unroll
    for (int i = 0; i < 16; ++i) {
        float4 w_, x_;
        w_ = Wk[i * 64 + lane]; x_ = xk[i * 64 + lane];
        ak += w_.x*x_.x + w_.y*x_.y + w_.z*x_.z + w_.w*x_.w;
        w_ = Wv[i * 64 + lane]; x_ = xv[i * 64 + lane];
        av += w_.x*x_.x + w_.y*x_.y + w_.z*x_.z + w_.w*x_.w;
        w_ = Wr[i * 64 + lane]; x_ = xr[i * 64 + lane];
        ar += w_.x*x_.x + w_.y*x_.y + w_.z*x_.z + w_.w*x_.w;
    }
    float kk = wave_reduce_sum(ak);
    float vv = wave_reduce_sum(av);
    float rr = wave_reduce_sum(ar);

    if (lane == 0) {
        int li = layer[0];
        float r  = 1.0f / (1.0f + expf(-rr));
        float aa = state[(size_t)(5 * li + 2) * NE + row];
        float bb = state[(size_t)(5 * li + 3) * NE + row];
        float pp = state[(size_t)(5 * li + 4) * NE + row];

        float ww = tf[row] + kk;
        float p  = fmaxf(pp, ww);
        float e1 = expf(pp - p);
        float e2 = expf(ww - p);
        float a  = e1 * aa + e2 * vv;
        float b  = e1 * bb + e2;

        float ww2 = pp + td[row];
        float p2  = fmaxf(ww2, kk);
        float e1s = expf(ww2 - p2);
        float e2s = expf(kk - p2);
        out_state[(size_t)(5 * li + 2) * NE + row] = e1s * aa + e2s * vv;
        out_state[(size_t)(5 * li + 3) * NE + row] = e1s * bb + e2s;
        out_state[(size_t)(5 * li + 4) * NE + row] = p2;

        rwkv[row] = r * (a / b);
    }
}

// ---------------- kernel 3: output matvec, full-row waves, rwkv in LDS ----------------
__global__ void __launch_bounds__(256)
k_matvec_ow(const float* __restrict__ ow, const float* __restrict__ rwkv,
            float* __restrict__ out) {
    __shared__ float4 sx[NE / 4];           // 16 KB
    int t    = threadIdx.x;
    int lane = t & 63;
    int row  = blockIdx.x * 4 + (t >> 6);
    #pragma unroll
    for (int j = 0; j < 4; ++j) sx[t + j * 256] = ((const float4*)rwkv)[t + j * 256];
    __syncthreads();

    const float4* Wr = (const float4*)(ow + (size_t)row * NE);
    float acc = 0.0f;
    #pragma unroll
    for (int i = 0; i < 16; ++i) {
        float4 w4 = Wr[i * 64 + lane];
        float4 x4 = sx[i * 64 + lane];
        acc += w4.x*x4.x + w4.y*x4.y + w4.z*x4.z + w4.w*x4.w;
    }
    acc = wave_reduce_sum(acc);
    if (lane == 0) out[row] = acc;
}

extern "C" void kernel_launch(void* const* d_in, const int* in_sizes, int n_in,
                              void* d_out, int out_size, void* d_ws, size_t ws_size,
                              hipStream_t stream) {
    const float* input = (const float*)d_in[0];
    const float* state = (const float*)d_in[1];
    const float* tmk   = (const float*)d_in[2];
    const float* tmv   = (const float*)d_in[3];
    const float* tmr   = (const float*)d_in[4];
    const float* tf    = (const float*)d_in[5];
    const float* td    = (const float*)d_in[6];
    const float* kw    = (const float*)d_in[7];
    const float* vw    = (const float*)d_in[8];
    const float* rw    = (const float*)d_in[9];
    const float* ow    = (const float*)d_in[10];
    const float* lnw   = (const float*)d_in[11];
    const float* lnb   = (const float*)d_in[12];
    const int*   layer = (const int*)d_in[13];

    float* out_state = (float*)d_out;                            // 160*4096 floats
    float* out_vec   = (float*)d_out + (size_t)NROWS_STATE * NE; // 4096 floats
    float* ws        = (float*)d_ws;

    // 1. state copy + layernorm + time-mix
    k_copy_ln_mix<<<641, 256, 0, stream>>>(input, state, tmk, tmv, tmr, lnw, lnb,
                                           layer, out_state, ws);
    // 2. kk/vv/rr matvecs + WKV recurrence, one wave per output index
    k_matvec3_wkv<<<NE / 4, 256, 0, stream>>>(kw, vw, rw, ws, state, tf, td,
                                              layer, out_state, ws + WS_RWKV);
    // 3. out = ow @ (r * wkv)
    k_matvec_ow<<<NE / 4, 256, 0, stream>>>(ow, ws + WS_RWKV, out_vec);
}

// Round 9
// 56.884 us; speedup vs baseline: 1.0427x; 1.0325x over previous
//
#include <hip/hip_runtime.h>
#include <math.h>

#define NE 4096
#define NROWS_STATE 160   // 5 * 32 layers

// ws layout (floats)
#define WS_XK   0
#define WS_XV   (NE)
#define WS_XR   (2*NE)
#define WS_KK   (3*NE)
#define WS_VV   (4*NE)
#define WS_RR   (5*NE)
#define WS_RWKV (6*NE)

__device__ __forceinline__ float wave_reduce_sum(float v) {
    #pragma unroll
    for (int off = 32; off > 0; off >>= 1)
        v += __shfl_down(v, off, 64);
    return v;  // valid in lane 0
}

// ---------------- kernel 1: state copy + accumulator zero + LN + time-mix ----------------
// block 0:        LN + mix (256 threads, 16 elems each)
// blocks 1..640:  copy state float4s, skipping rows 5i+1..5i+4
// blocks 641..656: zero the kk/vv/rr accumulators (3*NE) and out_vec (NE)
__global__ void __launch_bounds__(256)
k_copy_ln_mix(const float* __restrict__ in, const float* __restrict__ state,
              const float* __restrict__ tmk, const float* __restrict__ tmv,
              const float* __restrict__ tmr, const float* __restrict__ lnw,
              const float* __restrict__ lnb, const int* __restrict__ layer,
              float* __restrict__ out_state, float* __restrict__ out_vec,
              float* __restrict__ ws) {
    int li = layer[0];
    if (blockIdx.x >= 641) {
        // ---- zero accumulators ----
        int zidx = (blockIdx.x - 641) * 256 + threadIdx.x;    // float4 index 0..4095
        float4 z = make_float4(0.f, 0.f, 0.f, 0.f);
        if (zidx < 3 * NE / 4) ((float4*)(ws + WS_KK))[zidx] = z;
        else                   ((float4*)out_vec)[zidx - 3 * NE / 4] = z;
        return;
    }
    if (blockIdx.x != 0) {
        // ---- copy path ----
        int i4 = (blockIdx.x - 1) * 256 + threadIdx.x;   // float4 index, 1024 per row
        int row = i4 >> 10;
        if (row < 5 * li + 1 || row > 5 * li + 4) {
            ((float4*)out_state)[i4] = ((const float4*)state)[i4];
        }
        return;
    }
    // ---- LN + mix path (block 0) ----
    __shared__ float sm1[4];
    __shared__ float sm2[4];
    __shared__ float s_mu, s_rstd;
    int t = threadIdx.x;
    int lane = t & 63, wid = t >> 6;

    float4 v[4];
    float sum = 0.0f, sumsq = 0.0f;
    #pragma unroll
    for (int j = 0; j < 4; ++j) {
        v[j] = ((const float4*)in)[t * 4 + j];
        sum   += v[j].x + v[j].y + v[j].z + v[j].w;
        sumsq += v[j].x*v[j].x + v[j].y*v[j].y + v[j].z*v[j].z + v[j].w*v[j].w;
    }
    float s1 = wave_reduce_sum(sum);
    float s2 = wave_reduce_sum(sumsq);
    if (lane == 0) { sm1[wid] = s1; sm2[wid] = s2; }
    __syncthreads();
    if (t == 0) {
        float tot  = sm1[0] + sm1[1] + sm1[2] + sm1[3];
        float tot2 = sm2[0] + sm2[1] + sm2[2] + sm2[3];
        float mu  = tot * (1.0f / NE);
        float var = tot2 * (1.0f / NE) - mu * mu;
        s_mu = mu;
        s_rstd = rsqrtf(var + 1e-5f);
    }
    __syncthreads();
    float mu = s_mu, rstd = s_rstd;

    const float* prev_row = state + (size_t)(5 * li + 1) * NE;
    float* x_row = out_state + (size_t)(5 * li + 1) * NE;

    #pragma unroll
    for (int j = 0; j < 4; ++j) {
        #pragma unroll
        for (int c = 0; c < 4; ++c) {
            int idx = t * 16 + j * 4 + c;
            float xin = (c == 0) ? v[j].x : (c == 1) ? v[j].y : (c == 2) ? v[j].z : v[j].w;
            float x    = (xin - mu) * rstd * lnw[idx] + lnb[idx];
            float prev = prev_row[idx];
            float mk = tmk[idx], mv = tmv[idx], mr = tmr[idx];
            ws[WS_XK + idx] = x * mk + prev * (1.0f - mk);
            ws[WS_XV + idx] = x * mv + prev * (1.0f - mv);
            ws[WS_XR + idx] = x * mr + prev * (1.0f - mr);
            x_row[idx] = x;
        }
    }
}

// ---------------- kernel 2: fused 3-matrix matvec, segment-parallel ----------------
// 4 segments per row, one wave per (matrix,row,segment): 49152 waves, 12288 blocks.
// Copy-benchmark shape: short waves, rolled loads, no LDS, atomic accumulate.
__global__ void __launch_bounds__(256)
k_matvec3(const float* __restrict__ kw, const float* __restrict__ vw,
          const float* __restrict__ rw, const float* __restrict__ ws_in,
          float* __restrict__ ws_out) {
    int t    = threadIdx.x;
    int lane = t & 63;
    int g    = blockIdx.x * 4 + (t >> 6);   // global wave id
    int m    = g >> 14;                      // 16384 waves per matrix
    int rem  = g & 16383;
    int row  = rem >> 2;
    int seg  = rem & 3;
    const float* W = (m == 0) ? kw : (m == 1) ? vw : rw;
    const float4* Wr = (const float4*)(W + (size_t)row * NE) + seg * 256;
    const float4* xv = (const float4*)(ws_in + m * NE) + seg * 256;

    float acc = 0.0f;
    #pragma unroll
    for (int i = 0; i < 4; ++i) {
        float4 w4 = Wr[i * 64 + lane];
        float4 x4 = xv[i * 64 + lane];
        acc += w4.x*x4.x + w4.y*x4.y + w4.z*x4.z + w4.w*x4.w;
    }
    acc = wave_reduce_sum(acc);
    if (lane == 0) atomicAdd(&ws_out[m * NE + row], acc);
}

// ---------------- kernel 3: WKV elementwise + state update (sigmoid folded in) ----------------
__global__ void k_wkv(const float* __restrict__ state, const float* __restrict__ tf,
                      const float* __restrict__ td, const int* __restrict__ layer,
                      const float* __restrict__ ws, float* __restrict__ out_state,
                      float* __restrict__ rwkv) {
    int idx = blockIdx.x * blockDim.x + threadIdx.x;
    if (idx >= NE) return;
    int li = layer[0];
    float kk = ws[WS_KK + idx];
    float vv = ws[WS_VV + idx];
    float r  = 1.0f / (1.0f + expf(-ws[WS_RR + idx]));   // sigmoid here
    float aa = state[(size_t)(5 * li + 2) * NE + idx];
    float bb = state[(size_t)(5 * li + 3) * NE + idx];
    float pp = state[(size_t)(5 * li + 4) * NE + idx];

    float ww = tf[idx] + kk;
    float p  = fmaxf(pp, ww);
    float e1 = expf(pp - p);
    float e2 = expf(ww - p);
    float a  = e1 * aa + e2 * vv;
    float b  = e1 * bb + e2;

    float ww2 = pp + td[idx];
    float p2  = fmaxf(ww2, kk);
    float e1s = expf(ww2 - p2);
    float e2s = expf(kk - p2);
    out_state[(size_t)(5 * li + 2) * NE + idx] = e1s * aa + e2s * vv;
    out_state[(size_t)(5 * li + 3) * NE + idx] = e1s * bb + e2s;
    out_state[(size_t)(5 * li + 4) * NE + idx] = p2;

    rwkv[idx] = r * (a / b);
}

// ---------------- kernel 4: output matvec, segment-parallel ----------------
// 4 segments per row: 16384 waves, 4096 blocks. out_vec pre-zeroed in kernel 1.
__global__ void __launch_bounds__(256)
k_matvec_ow(const float* __restrict__ ow, const float* __restrict__ rwkv,
            float* __restrict__ out) {
    int t    = threadIdx.x;
    int lane = t & 63;
    int g    = blockIdx.x * 4 + (t >> 6);
    int row  = g >> 2;
    int seg  = g & 3;
    const float4* Wr = (const float4*)(ow + (size_t)row * NE) + seg * 256;
    const float4* xv = (const float4*)rwkv + seg * 256;

    float acc = 0.0f;
    #pragma unroll
    for (int i = 0; i < 4; ++i) {
        float4 w4 = Wr[i * 64 + lane];
        float4 x4 = xv[i * 64 + lane];
        acc += w4.x*x4.x + w4.y*x4.y + w4.z*x4.z + w4.w*x4.w;
    }
    acc = wave_reduce_sum(acc);
    if (lane == 0) atomicAdd(&out[row], acc);
}

extern "C" void kernel_launch(void* const* d_in, const int* in_sizes, int n_in,
                              void* d_out, int out_size, void* d_ws, size_t ws_size,
                              hipStream_t stream) {
    const float* input = (const float*)d_in[0];
    const float* state = (const float*)d_in[1];
    const float* tmk   = (const float*)d_in[2];
    const float* tmv   = (const float*)d_in[3];
    const float* tmr   = (const float*)d_in[4];
    const float* tf    = (const float*)d_in[5];
    const float* td    = (const float*)d_in[6];
    const float* kw    = (const float*)d_in[7];
    const float* vw    = (const float*)d_in[8];
    const float* rw    = (const float*)d_in[9];
    const float* ow    = (const float*)d_in[10];
    const float* lnw   = (const float*)d_in[11];
    const float* lnb   = (const float*)d_in[12];
    const int*   layer = (const int*)d_in[13];

    float* out_state = (float*)d_out;                            // 160*4096 floats
    float* out_vec   = (float*)d_out + (size_t)NROWS_STATE * NE; // 4096 floats
    float* ws        = (float*)d_ws;

    // 1. state copy + accumulator zeroing + layernorm + time-mix
    k_copy_ln_mix<<<657, 256, 0, stream>>>(input, state, tmk, tmv, tmr, lnw, lnb,
                                           layer, out_state, out_vec, ws);
    // 2. kk / vv / rr matvecs — 4 waves per row, atomic accumulate
    k_matvec3<<<3 * NE, 256, 0, stream>>>(kw, vw, rw, ws, ws + WS_KK);
    // 3. WKV recurrence (+ sigmoid of rr)
    k_wkv<<<NE / 256, 256, 0, stream>>>(state, tf, td, layer, ws, out_state,
                                        ws + WS_RWKV);
    // 4. out = ow @ (r * wkv) — 4 waves per row, atomic accumulate
    k_matvec_ow<<<NE, 256, 0, stream>>>(ow, ws + WS_RWKV, out_vec);
}